// Round 6
// baseline (602.050 us; speedup 1.0000x reference)
//
#include <hip/hip_runtime.h>

// VQ-VAE quantize: z [32,64,64,64] NCHW fp32, codebook [512,64] fp32.
// out = quantized [32,64,64,64] NCHW (8388608 floats) ++ loss scalar (1 float).
// N = 131072 positions, D = 64, K = 512.
//
// R6: R5 stalled at VALUBusy 30% because wave-uniform codebook loads became
// s_load (SMEM): SMEM shares lgkmcnt with ds_read and completes out-of-order,
// forcing lgkmcnt(0) drains (~460 stall cyc per 4-d chunk). Fix: force the
// codebook onto the VMEM pipe (vmcnt, independent counter, deep pipelining)
// via an asm-pinned vector base pointer; all lanes load the same address ->
// one L1 request, broadcast. Manual ping-pong prefetch (named float4 P*/Q*,
// depth 1) hides L1 latency behind the FMA block. z stays in LDS (4 in-order
// ds_read_b32 per chunk -> fine-grained lgkmcnt). Arithmetic unchanged from
// R5 (absmax 0.0): sequential-d FMA dot, pairwise-8 norms, (zn-2a)+cn,
// k-ascending strict < argmin.

#define Bz   32
#define Dz   64
#define HWz  4096
#define Nz   (Bz * HWz)         // 131072
#define Kz   512
#define QSIZE ((size_t)Nz * Dz) // 8388608

#define LD4(c, d0) (*(const float4*)(p + (c) * 256 + (d0) * 4))

#define LOADC(B, d0)                                                     \
    B##0  = LD4(0, d0);  B##1  = LD4(1, d0);  B##2  = LD4(2, d0);        \
    B##3  = LD4(3, d0);  B##4  = LD4(4, d0);  B##5  = LD4(5, d0);        \
    B##6  = LD4(6, d0);  B##7  = LD4(7, d0);  B##8  = LD4(8, d0);        \
    B##9  = LD4(9, d0);  B##10 = LD4(10, d0); B##11 = LD4(11, d0);       \
    B##12 = LD4(12, d0); B##13 = LD4(13, d0); B##14 = LD4(14, d0);       \
    B##15 = LD4(15, d0);

#define FMA1(B, c)                                                       \
    a##c = __builtin_fmaf(z0, B##c.x, a##c);                             \
    a##c = __builtin_fmaf(z1, B##c.y, a##c);                             \
    a##c = __builtin_fmaf(z2, B##c.z, a##c);                             \
    a##c = __builtin_fmaf(z3, B##c.w, a##c);

#define FMA16(B)                                                         \
    FMA1(B, 0)  FMA1(B, 1)  FMA1(B, 2)  FMA1(B, 3)                       \
    FMA1(B, 4)  FMA1(B, 5)  FMA1(B, 6)  FMA1(B, 7)                       \
    FMA1(B, 8)  FMA1(B, 9)  FMA1(B, 10) FMA1(B, 11)                      \
    FMA1(B, 12) FMA1(B, 13) FMA1(B, 14) FMA1(B, 15)

#define ZLOAD(d0)                                                        \
    z0 = zT[((d0) + 0) * 256 + t]; z1 = zT[((d0) + 1) * 256 + t];        \
    z2 = zT[((d0) + 2) * 256 + t]; z3 = zT[((d0) + 3) * 256 + t];

#define UPD(c)                                                           \
    {                                                                    \
        const float dist = (zn - 2.0f * a##c) + cnormS[k0 + (c)];        \
        if (dist < bd) { bd = dist; bk = k0 + (c); }                     \
    }

__global__ __launch_bounds__(256, 2) void vq_main(
    const float* __restrict__ z, const float* __restrict__ cb,
    float* __restrict__ out, float* __restrict__ loss_accum,
    unsigned int* __restrict__ done_counter) {
    __shared__ float zT[Dz * 256];   // zT[d*256 + p], d-major
    __shared__ float cnormS[Kz];
    __shared__ float wsum[4];

    const int t  = threadIdx.x;
    const int w  = t >> 6;           // wave id 0..3
    const int l  = t & 63;           // lane
    const int n0 = blockIdx.x * 256;
    const int b  = n0 >> 12;
    const int s0 = n0 & 4095;
    const float* zB = z + (size_t)b * (Dz * HWz);

    // ---- Stage zT: wave w loads rows d = 4i+w; lanes cover 256 consecutive
    // floats (1 KB/inst, fully coalesced).
#pragma unroll
    for (int i = 0; i < 16; ++i) {
        const int d = 4 * i + w;
        float4 f = *(const float4*)(zB + (size_t)d * HWz + s0 + 4 * l);
        *(float4*)(zT + d * 256 + 4 * l) = f;
    }

    // ---- cnorm for all 512 codes (numpy pairwise-8 exact; squares round
    // before add -> contraction off). 2 rows per thread.
    {
#pragma clang fp contract(off)
#pragma unroll
        for (int h = 0; h < 2; ++h) {
            const int k = t + 256 * h;
            const float4* row = (const float4*)(cb + (size_t)k * 64);
            float r0, r1, r2, r3, r4, r5, r6, r7;
            {
                float4 f0 = row[0], f1 = row[1];
                r0 = f0.x * f0.x; r1 = f0.y * f0.y; r2 = f0.z * f0.z; r3 = f0.w * f0.w;
                r4 = f1.x * f1.x; r5 = f1.y * f1.y; r6 = f1.z * f1.z; r7 = f1.w * f1.w;
            }
#pragma unroll
            for (int m = 1; m < 8; ++m) {
                float4 f0 = row[2 * m], f1 = row[2 * m + 1];
                r0 = r0 + f0.x * f0.x; r1 = r1 + f0.y * f0.y;
                r2 = r2 + f0.z * f0.z; r3 = r3 + f0.w * f0.w;
                r4 = r4 + f1.x * f1.x; r5 = r5 + f1.y * f1.y;
                r6 = r6 + f1.z * f1.z; r7 = r7 + f1.w * f1.w;
            }
            cnormS[k] = ((r0 + r1) + (r2 + r3)) + ((r4 + r5) + (r6 + r7));
        }
    }
    __syncthreads();

    // ---- znorm for this thread's position (pairwise-8 exact, from LDS).
    float zn;
    {
#pragma clang fp contract(off)
        float r0, r1, r2, r3, r4, r5, r6, r7;
        {
            float v0 = zT[0 * 256 + t], v1 = zT[1 * 256 + t];
            float v2 = zT[2 * 256 + t], v3 = zT[3 * 256 + t];
            float v4 = zT[4 * 256 + t], v5 = zT[5 * 256 + t];
            float v6 = zT[6 * 256 + t], v7 = zT[7 * 256 + t];
            r0 = v0 * v0; r1 = v1 * v1; r2 = v2 * v2; r3 = v3 * v3;
            r4 = v4 * v4; r5 = v5 * v5; r6 = v6 * v6; r7 = v7 * v7;
        }
#pragma unroll
        for (int m = 1; m < 8; ++m) {
            float v0 = zT[(8 * m + 0) * 256 + t], v1 = zT[(8 * m + 1) * 256 + t];
            float v2 = zT[(8 * m + 2) * 256 + t], v3 = zT[(8 * m + 3) * 256 + t];
            float v4 = zT[(8 * m + 4) * 256 + t], v5 = zT[(8 * m + 5) * 256 + t];
            float v6 = zT[(8 * m + 6) * 256 + t], v7 = zT[(8 * m + 7) * 256 + t];
            r0 = r0 + v0 * v0; r1 = r1 + v1 * v1; r2 = r2 + v2 * v2; r3 = r3 + v3 * v3;
            r4 = r4 + v4 * v4; r5 = r5 + v5 * v5; r6 = r6 + v6 * v6; r7 = r7 + v7 * v7;
        }
        zn = ((r0 + r1) + (r2 + r3)) + ((r4 + r5) + (r6 + r7));
    }

    // ---- K loop: 32 groups of 16 codes. No barriers; codebook via VMEM
    // broadcast (vmcnt) with depth-1 ping-pong prefetch; z via in-order LDS.
    float bd = __builtin_inff();
    int   bk = 0;
#pragma unroll 1
    for (int k0 = 0; k0 < Kz; k0 += 16) {
        const char* p = (const char*)cb + (size_t)k0 * 256;
        asm volatile("" : "+v"(p));   // vector address -> global_load, vmcnt
        float a0 = 0.f, a1 = 0.f, a2 = 0.f, a3 = 0.f;
        float a4 = 0.f, a5 = 0.f, a6 = 0.f, a7 = 0.f;
        float a8 = 0.f, a9 = 0.f, a10 = 0.f, a11 = 0.f;
        float a12 = 0.f, a13 = 0.f, a14 = 0.f, a15 = 0.f;
        float4 P0, P1, P2, P3, P4, P5, P6, P7;
        float4 P8, P9, P10, P11, P12, P13, P14, P15;
        float4 Q0, Q1, Q2, Q3, Q4, Q5, Q6, Q7;
        float4 Q8, Q9, Q10, Q11, Q12, Q13, Q14, Q15;
        float z0, z1, z2, z3;
        LOADC(P, 0)
#pragma unroll
        for (int d0 = 0; d0 < 64; d0 += 8) {
            ZLOAD(d0)
            LOADC(Q, d0 + 4)          // prefetch next chunk while FMA-ing P
            FMA16(P)
            ZLOAD(d0 + 4)
            if (d0 + 8 < 64) { LOADC(P, d0 + 8) }
            FMA16(Q)
        }
        UPD(0)  UPD(1)  UPD(2)  UPD(3)
        UPD(4)  UPD(5)  UPD(6)  UPD(7)
        UPD(8)  UPD(9)  UPD(10) UPD(11)
        UPD(12) UPD(13) UPD(14) UPD(15)
    }

    // ---- Epilogue: gather chosen code, write q_st (NCHW coalesced), loss.
    const float* q = cb + (size_t)bk * 64;
    float* oB = out + (size_t)b * (Dz * HWz) + s0 + t;
    float lsum = 0.f;
#pragma unroll
    for (int d0 = 0; d0 < 64; d0 += 4) {
        const float4 q4 = *(const float4*)(q + d0);
        const float y0 = zT[(d0 + 0) * 256 + t];
        const float y1 = zT[(d0 + 1) * 256 + t];
        const float y2 = zT[(d0 + 2) * 256 + t];
        const float y3 = zT[(d0 + 3) * 256 + t];
        const float e0 = y0 - q4.x, e1 = y1 - q4.y;
        const float e2 = y2 - q4.z, e3 = y3 - q4.w;
        lsum += e0 * e0; lsum += e1 * e1; lsum += e2 * e2; lsum += e3 * e3;
        oB[(size_t)(d0 + 0) * HWz] = y0 + (q4.x - y0);
        oB[(size_t)(d0 + 1) * HWz] = y1 + (q4.y - y1);
        oB[(size_t)(d0 + 2) * HWz] = y2 + (q4.z - y2);
        oB[(size_t)(d0 + 3) * HWz] = y3 + (q4.w - y3);
    }

    // ---- Loss reduction: wave shuffle -> LDS -> one atomic -> ticket.
#pragma unroll
    for (int off = 32; off > 0; off >>= 1) lsum += __shfl_down(lsum, off, 64);
    if (l == 0) wsum[w] = lsum;
    __syncthreads();
    if (t == 0) {
        float tot = (wsum[0] + wsum[1]) + (wsum[2] + wsum[3]);
        atomicAdd(loss_accum, tot);
        __threadfence();
        unsigned int ticket = atomicAdd(done_counter, 1u);
        if (ticket == gridDim.x - 1) {
            __threadfence();
            float total = atomicAdd(loss_accum, 0.0f);
            float X = total / (float)QSIZE;
            out[QSIZE] = X + 0.25f * X;
        }
    }
}

extern "C" void kernel_launch(void* const* d_in, const int* in_sizes, int n_in,
                              void* d_out, int out_size, void* d_ws, size_t ws_size,
                              hipStream_t stream) {
    const float* z  = (const float*)d_in[0];
    const float* cb = (const float*)d_in[1];
    float* out = (float*)d_out;
    float* wsf = (float*)d_ws;
    hipMemsetAsync(d_ws, 0, 8, stream);
    vq_main<<<Nz / 256, 256, 0, stream>>>(z, cb, out, wsf, (unsigned int*)(wsf + 1));
}

// Round 7
// 563.690 us; speedup vs baseline: 1.0681x; 1.0681x over previous
//
#include <hip/hip_runtime.h>

// VQ-VAE quantize: z [32,64,64,64] NCHW fp32, codebook [512,64] fp32.
// out = quantized [32,64,64,64] NCHW (8388608 floats) ++ loss scalar (1 float).
// N = 131072 positions, D = 64, K = 512.
//
// R7: R6's pipe split was right (z on lgkmcnt via LDS, codebook on vmcnt via
// VMEM broadcast loads), but the P/Q ping-pong (128 VGPRs of buffers) spilled
// (WRITE_SIZE +20MB of scratch). R7 uses ONE 16-quad buffer (64 regs): issue
// 4 ds_read(z), issue 16 global_load_dwordx4(c), lgkmcnt(0) waits only z,
// FMAs drain on fine-grained vmcnt in load order. ~100 VGPRs -> no spill.
// Second wave/SIMD covers the per-chunk L1 latency bubble. Arithmetic is
// bit-identical to R1/R5 (absmax 0.0): sequential-d FMA dot, pairwise-8
// norms, (zn-2a)+cn, k-ascending strict < argmin.

#define Bz   32
#define Dz   64
#define HWz  4096
#define Nz   (Bz * HWz)         // 131072
#define Kz   512
#define QSIZE ((size_t)Nz * Dz) // 8388608

#define LD4(c) (*(const float4*)(p + (c) * 256))

#define LOADC16()                                                        \
    C0  = LD4(0);  C1  = LD4(1);  C2  = LD4(2);  C3  = LD4(3);           \
    C4  = LD4(4);  C5  = LD4(5);  C6  = LD4(6);  C7  = LD4(7);           \
    C8  = LD4(8);  C9  = LD4(9);  C10 = LD4(10); C11 = LD4(11);          \
    C12 = LD4(12); C13 = LD4(13); C14 = LD4(14); C15 = LD4(15);

#define FMA1(c)                                                          \
    a##c = __builtin_fmaf(z0, C##c.x, a##c);                             \
    a##c = __builtin_fmaf(z1, C##c.y, a##c);                             \
    a##c = __builtin_fmaf(z2, C##c.z, a##c);                             \
    a##c = __builtin_fmaf(z3, C##c.w, a##c);

#define FMA16()                                                          \
    FMA1(0)  FMA1(1)  FMA1(2)  FMA1(3)                                   \
    FMA1(4)  FMA1(5)  FMA1(6)  FMA1(7)                                   \
    FMA1(8)  FMA1(9)  FMA1(10) FMA1(11)                                  \
    FMA1(12) FMA1(13) FMA1(14) FMA1(15)

#define UPD(c)                                                           \
    {                                                                    \
        const float dist = (zn - 2.0f * a##c) + cnormS[k0 + (c)];        \
        if (dist < bd) { bd = dist; bk = k0 + (c); }                     \
    }

__global__ __launch_bounds__(256, 2) void vq_main(
    const float* __restrict__ z, const float* __restrict__ cb,
    float* __restrict__ out, float* __restrict__ loss_accum,
    unsigned int* __restrict__ done_counter) {
    __shared__ float zT[Dz * 256];   // zT[d*256 + p], d-major
    __shared__ float cnormS[Kz];
    __shared__ float wsum[4];

    const int t  = threadIdx.x;
    const int w  = t >> 6;           // wave id 0..3
    const int l  = t & 63;           // lane
    const int n0 = blockIdx.x * 256;
    const int b  = n0 >> 12;
    const int s0 = n0 & 4095;
    const float* zB = z + (size_t)b * (Dz * HWz);

    // ---- Stage zT: wave w loads rows d = 4i+w; lanes cover 256 consecutive
    // floats (1 KB/inst, fully coalesced).
#pragma unroll
    for (int i = 0; i < 16; ++i) {
        const int d = 4 * i + w;
        float4 f = *(const float4*)(zB + (size_t)d * HWz + s0 + 4 * l);
        *(float4*)(zT + d * 256 + 4 * l) = f;
    }

    // ---- cnorm for all 512 codes (numpy pairwise-8 exact; squares round
    // before add -> contraction off). 2 rows per thread.
    {
#pragma clang fp contract(off)
#pragma unroll
        for (int h = 0; h < 2; ++h) {
            const int k = t + 256 * h;
            const float4* row = (const float4*)(cb + (size_t)k * 64);
            float r0, r1, r2, r3, r4, r5, r6, r7;
            {
                float4 f0 = row[0], f1 = row[1];
                r0 = f0.x * f0.x; r1 = f0.y * f0.y; r2 = f0.z * f0.z; r3 = f0.w * f0.w;
                r4 = f1.x * f1.x; r5 = f1.y * f1.y; r6 = f1.z * f1.z; r7 = f1.w * f1.w;
            }
#pragma unroll
            for (int m = 1; m < 8; ++m) {
                float4 f0 = row[2 * m], f1 = row[2 * m + 1];
                r0 = r0 + f0.x * f0.x; r1 = r1 + f0.y * f0.y;
                r2 = r2 + f0.z * f0.z; r3 = r3 + f0.w * f0.w;
                r4 = r4 + f1.x * f1.x; r5 = r5 + f1.y * f1.y;
                r6 = r6 + f1.z * f1.z; r7 = r7 + f1.w * f1.w;
            }
            cnormS[k] = ((r0 + r1) + (r2 + r3)) + ((r4 + r5) + (r6 + r7));
        }
    }
    __syncthreads();

    // ---- znorm for this thread's position (pairwise-8 exact, from LDS).
    float zn;
    {
#pragma clang fp contract(off)
        float r0, r1, r2, r3, r4, r5, r6, r7;
        {
            float v0 = zT[0 * 256 + t], v1 = zT[1 * 256 + t];
            float v2 = zT[2 * 256 + t], v3 = zT[3 * 256 + t];
            float v4 = zT[4 * 256 + t], v5 = zT[5 * 256 + t];
            float v6 = zT[6 * 256 + t], v7 = zT[7 * 256 + t];
            r0 = v0 * v0; r1 = v1 * v1; r2 = v2 * v2; r3 = v3 * v3;
            r4 = v4 * v4; r5 = v5 * v5; r6 = v6 * v6; r7 = v7 * v7;
        }
#pragma unroll
        for (int m = 1; m < 8; ++m) {
            float v0 = zT[(8 * m + 0) * 256 + t], v1 = zT[(8 * m + 1) * 256 + t];
            float v2 = zT[(8 * m + 2) * 256 + t], v3 = zT[(8 * m + 3) * 256 + t];
            float v4 = zT[(8 * m + 4) * 256 + t], v5 = zT[(8 * m + 5) * 256 + t];
            float v6 = zT[(8 * m + 6) * 256 + t], v7 = zT[(8 * m + 7) * 256 + t];
            r0 = r0 + v0 * v0; r1 = r1 + v1 * v1; r2 = r2 + v2 * v2; r3 = r3 + v3 * v3;
            r4 = r4 + v4 * v4; r5 = r5 + v5 * v5; r6 = r6 + v6 * v6; r7 = r7 + v7 * v7;
        }
        zn = ((r0 + r1) + (r2 + r3)) + ((r4 + r5) + (r6 + r7));
    }

    // ---- K loop: 32 groups of 16 codes. z via in-order LDS (lgkmcnt only
    // has the 4 ds_reads in flight); codebook via VMEM broadcast (vmcnt),
    // consumed in load order so the compiler emits fine-grained vmcnt(N).
    float bd = __builtin_inff();
    int   bk = 0;
#pragma unroll 1
    for (int k0 = 0; k0 < Kz; k0 += 16) {
        const char* p = (const char*)cb + (size_t)k0 * 256;
        asm volatile("" : "+v"(p));   // vector address -> global_load, vmcnt
        float a0 = 0.f, a1 = 0.f, a2 = 0.f, a3 = 0.f;
        float a4 = 0.f, a5 = 0.f, a6 = 0.f, a7 = 0.f;
        float a8 = 0.f, a9 = 0.f, a10 = 0.f, a11 = 0.f;
        float a12 = 0.f, a13 = 0.f, a14 = 0.f, a15 = 0.f;
#pragma unroll 1
        for (int d0 = 0; d0 < 64; d0 += 4, p += 16) {
            const float z0 = zT[(d0 + 0) * 256 + t];
            const float z1 = zT[(d0 + 1) * 256 + t];
            const float z2 = zT[(d0 + 2) * 256 + t];
            const float z3 = zT[(d0 + 3) * 256 + t];
            float4 C0, C1, C2, C3, C4, C5, C6, C7;
            float4 C8, C9, C10, C11, C12, C13, C14, C15;
            LOADC16()
            FMA16()
        }
        UPD(0)  UPD(1)  UPD(2)  UPD(3)
        UPD(4)  UPD(5)  UPD(6)  UPD(7)
        UPD(8)  UPD(9)  UPD(10) UPD(11)
        UPD(12) UPD(13) UPD(14) UPD(15)
    }

    // ---- Epilogue: gather chosen code, write q_st (NCHW coalesced), loss.
    const float* q = cb + (size_t)bk * 64;
    float* oB = out + (size_t)b * (Dz * HWz) + s0 + t;
    float lsum = 0.f;
#pragma unroll
    for (int d0 = 0; d0 < 64; d0 += 4) {
        const float4 q4 = *(const float4*)(q + d0);
        const float y0 = zT[(d0 + 0) * 256 + t];
        const float y1 = zT[(d0 + 1) * 256 + t];
        const float y2 = zT[(d0 + 2) * 256 + t];
        const float y3 = zT[(d0 + 3) * 256 + t];
        const float e0 = y0 - q4.x, e1 = y1 - q4.y;
        const float e2 = y2 - q4.z, e3 = y3 - q4.w;
        lsum += e0 * e0; lsum += e1 * e1; lsum += e2 * e2; lsum += e3 * e3;
        oB[(size_t)(d0 + 0) * HWz] = y0 + (q4.x - y0);
        oB[(size_t)(d0 + 1) * HWz] = y1 + (q4.y - y1);
        oB[(size_t)(d0 + 2) * HWz] = y2 + (q4.z - y2);
        oB[(size_t)(d0 + 3) * HWz] = y3 + (q4.w - y3);
    }

    // ---- Loss reduction: wave shuffle -> LDS -> one atomic -> ticket.
#pragma unroll
    for (int off = 32; off > 0; off >>= 1) lsum += __shfl_down(lsum, off, 64);
    if (l == 0) wsum[w] = lsum;
    __syncthreads();
    if (t == 0) {
        float tot = (wsum[0] + wsum[1]) + (wsum[2] + wsum[3]);
        atomicAdd(loss_accum, tot);
        __threadfence();
        unsigned int ticket = atomicAdd(done_counter, 1u);
        if (ticket == gridDim.x - 1) {
            __threadfence();
            float total = atomicAdd(loss_accum, 0.0f);
            float X = total / (float)QSIZE;
            out[QSIZE] = X + 0.25f * X;
        }
    }
}

extern "C" void kernel_launch(void* const* d_in, const int* in_sizes, int n_in,
                              void* d_out, int out_size, void* d_ws, size_t ws_size,
                              hipStream_t stream) {
    const float* z  = (const float*)d_in[0];
    const float* cb = (const float*)d_in[1];
    float* out = (float*)d_out;
    float* wsf = (float*)d_ws;
    hipMemsetAsync(d_ws, 0, 8, stream);
    vq_main<<<Nz / 256, 256, 0, stream>>>(z, cb, out, wsf, (unsigned int*)(wsf + 1));
}

// Round 8
// 170.958 us; speedup vs baseline: 3.5216x; 3.2972x over previous
//
#include <hip/hip_runtime.h>

// VQ-VAE quantize: z [32,64,64,64] NCHW fp32, codebook [512,64] fp32.
// out = quantized (8388608 fp32, NCHW) ++ loss scalar. N=131072, D=64, K=512.
//
// R8: MFMA bf16-split distance GEMM. R5-R7 proved the vector path is
// operand-bandwidth-bound (every lane needs all 512x64 codebook values;
// SMEM/LDS/VMEM broadcast all stall). MFMA shares operands in HW.
// argmin rank = cn - 2*dot (zn constant per row). dot via 3-pass hi/lo bf16
// split MFMA (err <= ~5e-4). Rows whose approx best-vs-second gap <= 4e-3
// (incl. all ties) fall back to a block-cooperative np-BIT-EXACT rescan
// (R5-validated chain). Output values are exact gathers -> absmax 0.0.

typedef __bf16 bf8 __attribute__((ext_vector_type(8)));
typedef float  f4  __attribute__((ext_vector_type(4)));

#define Dz    64
#define HWz   4096
#define Nz    131072
#define QSIZE ((size_t)Nz * Dz)     // 8388608
#define PSTR  132                   // zT row stride (floats)
#define CROW  72                    // split-cb row stride (ushorts) = 144B
#define TILE_USHORT 18432           // one 128-code tile (hi+lo) in ushorts
#define CB_WS_BYTES (4 * 36864)     // 147456
#define TAU   4e-3f

#define MFMA(A, B, C) __builtin_amdgcn_mfma_f32_16x16x32_bf16(A, B, C, 0, 0, 0)

// ---------- prep: split codebook to bf16 hi/lo (padded tiles) + exact cn ----
__global__ __launch_bounds__(256) void vq_prep(const float* __restrict__ cb,
                                               unsigned short* __restrict__ cbws,
                                               float* __restrict__ cnws) {
    const int k = blockIdx.x * 256 + threadIdx.x;   // 0..511
    const float4* row = (const float4*)(cb + (size_t)k * 64);
    {   // numpy pairwise-8 sumsq (squares round before add)
#pragma clang fp contract(off)
        float r0, r1, r2, r3, r4, r5, r6, r7;
        {
            float4 f0 = row[0], f1 = row[1];
            r0 = f0.x * f0.x; r1 = f0.y * f0.y; r2 = f0.z * f0.z; r3 = f0.w * f0.w;
            r4 = f1.x * f1.x; r5 = f1.y * f1.y; r6 = f1.z * f1.z; r7 = f1.w * f1.w;
        }
#pragma unroll
        for (int m = 1; m < 8; ++m) {
            float4 f0 = row[2 * m], f1 = row[2 * m + 1];
            r0 = r0 + f0.x * f0.x; r1 = r1 + f0.y * f0.y;
            r2 = r2 + f0.z * f0.z; r3 = r3 + f0.w * f0.w;
            r4 = r4 + f1.x * f1.x; r5 = r5 + f1.y * f1.y;
            r6 = r6 + f1.z * f1.z; r7 = r7 + f1.w * f1.w;
        }
        cnws[k] = ((r0 + r1) + (r2 + r3)) + ((r4 + r5) + (r6 + r7));
    }
    unsigned short* hi = cbws + (size_t)(k >> 7) * TILE_USHORT + (k & 127) * CROW;
    unsigned short* lo = hi + TILE_USHORT / 2;      // +9216 ushorts = 18432B
#define SPLIT1(x, i)                                                   \
    {   __bf16 h = (__bf16)(x); float rr = (x) - (float)h;             \
        hi[i] = __builtin_bit_cast(unsigned short, h);                 \
        lo[i] = __builtin_bit_cast(unsigned short, (__bf16)rr); }
#pragma unroll
    for (int i = 0; i < 16; ++i) {
        float4 f = row[i];
        SPLIT1(f.x, 4 * i + 0) SPLIT1(f.y, 4 * i + 1)
        SPLIT1(f.z, 4 * i + 2) SPLIT1(f.w, 4 * i + 3)
    }
#undef SPLIT1
}

// ---------- main ----------
#define DECL8(P) float P##0, P##1, P##2, P##3, P##4, P##5, P##6, P##7;
#define DECI8(P) int   P##0, P##1, P##2, P##3, P##4, P##5, P##6, P##7;

// best/second update: order matters (second from OLD best).
#define UPDR(ACCE, B, K, S)                                            \
    {   const float vv = __builtin_fmaf(ACCE, -2.0f, cnv);             \
        S = fminf(S, fmaxf(B, vv));                                    \
        K = (vv < B) ? kcand : K;                                      \
        B = fminf(B, vv); }

#define REDR(B, K, S)                                                  \
    _Pragma("unroll")                                                  \
    for (int mm = 1; mm < 16; mm <<= 1) {                              \
        const float ob = __shfl_xor(B, mm, 64);                        \
        const int   ok = __shfl_xor(K, mm, 64);                        \
        const float os = __shfl_xor(S, mm, 64);                        \
        S = fminf(fminf(S, os), fmaxf(B, ob));                         \
        K = (ob < B) ? ok : K;                                         \
        B = fminf(B, ob); }

__global__ __launch_bounds__(256, 2) void vq_main(
    const float* __restrict__ z, const float* __restrict__ cb,
    const unsigned short* __restrict__ cbws, const float* __restrict__ cnws,
    float* __restrict__ out, float* __restrict__ loss_accum,
    unsigned int* __restrict__ done_counter) {
    __shared__ float  zT[Dz * PSTR];        // zT[d*PSTR + p], 128 positions
    __shared__ unsigned short cbS[TILE_USHORT];
    __shared__ float  cn_s[512];
    __shared__ int    idx_s[128];
    __shared__ float  wredD[4];
    __shared__ int    wredK[4];
    __shared__ float  wsum[4];

    const int t  = threadIdx.x;
    const int w  = t >> 6;
    const int l  = t & 63;
    const int q  = l >> 4;
    const int m16 = l & 15;
    const int n0g = blockIdx.x * 128;
    const int b   = n0g >> 12;
    const int s0  = n0g & 4095;
    const float* zB = z + (size_t)b * (Dz * HWz);

    // ---- stage zT: 2048 float4s, flat. d = flat>>5, col4 = flat&31.
#pragma unroll
    for (int i = 0; i < 8; ++i) {
        const int flat = t + 256 * i;
        const int d = flat >> 5, c4 = flat & 31;
        float4 f = *(const float4*)(zB + (size_t)d * HWz + s0 + 4 * c4);
        *(float4*)(zT + d * PSTR + 4 * c4) = f;
    }
    // ---- stage cn (512 floats = 128 f4)
    if (t < 128) ((float4*)cn_s)[t] = ((const float4*)cnws)[t];
    __syncthreads();

    // ---- build A fragments (registers, for both 16-pos tiles, hi+lo, 2 k-chunks)
    bf8 ah00, ah01, al00, al01, ah10, ah11, al10, al11;
    {
        const int pA = 32 * w + m16, pB = pA + 16;
#define BUILDA(AH, AL, P, KC)                                          \
        _Pragma("unroll")                                              \
        for (int j = 0; j < 8; ++j) {                                  \
            const float v = zT[((KC) * 32 + q * 8 + j) * PSTR + (P)];  \
            const __bf16 h = (__bf16)v;                                \
            AH[j] = h;                                                 \
            AL[j] = (__bf16)(v - (float)h);                            \
        }
        BUILDA(ah00, al00, pA, 0) BUILDA(ah01, al01, pA, 1)
        BUILDA(ah10, al10, pB, 0) BUILDA(ah11, al11, pB, 1)
#undef BUILDA
    }

    // ---- K loop: 4 tiles x 128 codes. Rows per lane: tile0 regs->b0..3,
    // tile1 regs->b4..7. Each lane tracks one column (code) per subtile.
    const float INF = __builtin_inff();
    DECL8(bd) DECI8(bk) DECL8(sd)
    bd0=INF;bd1=INF;bd2=INF;bd3=INF;bd4=INF;bd5=INF;bd6=INF;bd7=INF;
    sd0=INF;sd1=INF;sd2=INF;sd3=INF;sd4=INF;sd5=INF;sd6=INF;sd7=INF;
    bk0=0;bk1=0;bk2=0;bk3=0;bk4=0;bk5=0;bk6=0;bk7=0;

    for (int kt = 0; kt < 4; ++kt) {
        __syncthreads();
        {   // flat copy one split tile (36864B = 2304 f4) into LDS
            const float4* src = (const float4*)(cbws + (size_t)kt * TILE_USHORT);
            float4* dst = (float4*)cbS;
#pragma unroll
            for (int i = 0; i < 9; ++i) dst[t + 256 * i] = src[t + 256 * i];
        }
        __syncthreads();
        const int k0 = kt * 128;
#pragma unroll 2
        for (int n0 = 0; n0 < 128; n0 += 16) {
            const int nlane = n0 + m16;
            const int hoff = nlane * CROW + q * 8;          // ushorts
            const bf8 bh0 = *(const bf8*)(cbS + hoff);
            const bf8 bh1 = *(const bf8*)(cbS + hoff + 32);
            const bf8 bl0 = *(const bf8*)(cbS + hoff + TILE_USHORT / 2);
            const bf8 bl1 = *(const bf8*)(cbS + hoff + TILE_USHORT / 2 + 32);
            f4 acc0 = {0.f, 0.f, 0.f, 0.f}, acc1 = {0.f, 0.f, 0.f, 0.f};
            acc0 = MFMA(ah00, bh0, acc0); acc0 = MFMA(ah01, bh1, acc0);
            acc1 = MFMA(ah10, bh0, acc1); acc1 = MFMA(ah11, bh1, acc1);
            acc0 = MFMA(al00, bh0, acc0); acc0 = MFMA(al01, bh1, acc0);
            acc1 = MFMA(al10, bh0, acc1); acc1 = MFMA(al11, bh1, acc1);
            acc0 = MFMA(ah00, bl0, acc0); acc0 = MFMA(ah01, bl1, acc0);
            acc1 = MFMA(ah10, bl0, acc1); acc1 = MFMA(ah11, bl1, acc1);
            const float cnv = cn_s[k0 + nlane];
            const int kcand = k0 + nlane;
            UPDR(acc0[0], bd0, bk0, sd0) UPDR(acc0[1], bd1, bk1, sd1)
            UPDR(acc0[2], bd2, bk2, sd2) UPDR(acc0[3], bd3, bk3, sd3)
            UPDR(acc1[0], bd4, bk4, sd4) UPDR(acc1[1], bd5, bk5, sd5)
            UPDR(acc1[2], bd6, bk6, sd6) UPDR(acc1[3], bd7, bk7, sd7)
        }
    }

    // ---- cross-lane reduce (16-lane groups hold one row each) + flag.
    REDR(bd0, bk0, sd0) REDR(bd1, bk1, sd1) REDR(bd2, bk2, sd2) REDR(bd3, bk3, sd3)
    REDR(bd4, bk4, sd4) REDR(bd5, bk5, sd5) REDR(bd6, bk6, sd6) REDR(bd7, bk7, sd7)
    if (m16 == 0) {
        const int base = 32 * w + 4 * q;
        idx_s[base + 0]      = (sd0 - bd0 <= TAU) ? -1 : bk0;
        idx_s[base + 1]      = (sd1 - bd1 <= TAU) ? -1 : bk1;
        idx_s[base + 2]      = (sd2 - bd2 <= TAU) ? -1 : bk2;
        idx_s[base + 3]      = (sd3 - bd3 <= TAU) ? -1 : bk3;
        idx_s[base + 16 + 0] = (sd4 - bd4 <= TAU) ? -1 : bk4;
        idx_s[base + 16 + 1] = (sd5 - bd5 <= TAU) ? -1 : bk5;
        idx_s[base + 16 + 2] = (sd6 - bd6 <= TAU) ? -1 : bk6;
        idx_s[base + 16 + 3] = (sd7 - bd7 <= TAU) ? -1 : bk7;
    }
    __syncthreads();

    // ---- fallback: np-bit-exact rescan for flagged rows (rare).
    for (int row = 0; row < 128; ++row) {
        if (idx_s[row] >= 0) continue;     // block-uniform branch
        float zn;
        {   // np pairwise-8 znorm from LDS (broadcast reads)
#pragma clang fp contract(off)
            float r0, r1, r2, r3, r4, r5, r6, r7;
            r0 = zT[0*PSTR+row]*zT[0*PSTR+row]; r1 = zT[1*PSTR+row]*zT[1*PSTR+row];
            r2 = zT[2*PSTR+row]*zT[2*PSTR+row]; r3 = zT[3*PSTR+row]*zT[3*PSTR+row];
            r4 = zT[4*PSTR+row]*zT[4*PSTR+row]; r5 = zT[5*PSTR+row]*zT[5*PSTR+row];
            r6 = zT[6*PSTR+row]*zT[6*PSTR+row]; r7 = zT[7*PSTR+row]*zT[7*PSTR+row];
#pragma unroll
            for (int m = 1; m < 8; ++m) {
                float v0 = zT[(8*m+0)*PSTR+row], v1 = zT[(8*m+1)*PSTR+row];
                float v2 = zT[(8*m+2)*PSTR+row], v3 = zT[(8*m+3)*PSTR+row];
                float v4 = zT[(8*m+4)*PSTR+row], v5 = zT[(8*m+5)*PSTR+row];
                float v6 = zT[(8*m+6)*PSTR+row], v7 = zT[(8*m+7)*PSTR+row];
                r0 = r0 + v0*v0; r1 = r1 + v1*v1; r2 = r2 + v2*v2; r3 = r3 + v3*v3;
                r4 = r4 + v4*v4; r5 = r5 + v5*v5; r6 = r6 + v6*v6; r7 = r7 + v7*v7;
            }
            zn = ((r0 + r1) + (r2 + r3)) + ((r4 + r5) + (r6 + r7));
        }
        float bd; int bk;
        {   // codes t and t+256, exact sequential-d chain (R5-validated)
            float dd[2];
#pragma unroll
            for (int h = 0; h < 2; ++h) {
                const int k = t + 256 * h;
                const float4* C = (const float4*)(cb + (size_t)k * 64);
                float a = 0.f;
#pragma unroll
                for (int i = 0; i < 16; ++i) {
                    const float4 c4 = C[i];
                    a = __builtin_fmaf(zT[(4*i+0)*PSTR+row], c4.x, a);
                    a = __builtin_fmaf(zT[(4*i+1)*PSTR+row], c4.y, a);
                    a = __builtin_fmaf(zT[(4*i+2)*PSTR+row], c4.z, a);
                    a = __builtin_fmaf(zT[(4*i+3)*PSTR+row], c4.w, a);
                }
                dd[h] = (zn - 2.0f * a) + cn_s[k];
            }
            bd = dd[0]; bk = t;
            if (dd[1] < bd) { bd = dd[1]; bk = t + 256; }
        }
#pragma unroll
        for (int mm = 1; mm < 64; mm <<= 1) {
            const float ob = __shfl_xor(bd, mm, 64);
            const int   ok = __shfl_xor(bk, mm, 64);
            if (ob < bd || (ob == bd && ok < bk)) { bd = ob; bk = ok; }
        }
        if (l == 0) { wredD[w] = bd; wredK[w] = bk; }
        __syncthreads();
        if (t == 0) {
            float fb = wredD[0]; int fk = wredK[0];
#pragma unroll
            for (int i = 1; i < 4; ++i) {
                if (wredD[i] < fb || (wredD[i] == fb && wredK[i] < fk)) {
                    fb = wredD[i]; fk = wredK[i];
                }
            }
            idx_s[row] = fk;
        }
        __syncthreads();
    }
    __syncthreads();

    // ---- epilogue: gather code, write q_st (NCHW coalesced), loss.
    const int p  = t & 127;
    const int d0 = (t >> 7) * 32;
    const int myidx = idx_s[p];
    const float* qrow = cb + (size_t)myidx * 64 + d0;
    float* oB = out + (size_t)b * (Dz * HWz) + s0 + p;
    float lsum = 0.f;
#pragma unroll
    for (int j = 0; j < 8; ++j) {
        const int d = d0 + 4 * j;
        const float4 q4 = *(const float4*)(qrow + 4 * j);
        const float y0 = zT[(d + 0) * PSTR + p];
        const float y1 = zT[(d + 1) * PSTR + p];
        const float y2 = zT[(d + 2) * PSTR + p];
        const float y3 = zT[(d + 3) * PSTR + p];
        const float e0 = y0 - q4.x, e1 = y1 - q4.y;
        const float e2 = y2 - q4.z, e3 = y3 - q4.w;
        lsum += e0 * e0; lsum += e1 * e1; lsum += e2 * e2; lsum += e3 * e3;
        oB[(size_t)(d + 0) * HWz] = y0 + (q4.x - y0);
        oB[(size_t)(d + 1) * HWz] = y1 + (q4.y - y1);
        oB[(size_t)(d + 2) * HWz] = y2 + (q4.z - y2);
        oB[(size_t)(d + 3) * HWz] = y3 + (q4.w - y3);
    }
#pragma unroll
    for (int off = 32; off > 0; off >>= 1) lsum += __shfl_down(lsum, off, 64);
    if (l == 0) wsum[w] = lsum;
    __syncthreads();
    if (t == 0) {
        float tot = (wsum[0] + wsum[1]) + (wsum[2] + wsum[3]);
        atomicAdd(loss_accum, tot);
        __threadfence();
        unsigned int ticket = atomicAdd(done_counter, 1u);
        if (ticket == gridDim.x - 1) {
            __threadfence();
            float total = atomicAdd(loss_accum, 0.0f);
            float X = total / (float)QSIZE;
            out[QSIZE] = X + 0.25f * X;
        }
    }
}

extern "C" void kernel_launch(void* const* d_in, const int* in_sizes, int n_in,
                              void* d_out, int out_size, void* d_ws, size_t ws_size,
                              hipStream_t stream) {
    const float* z  = (const float*)d_in[0];
    const float* cb = (const float*)d_in[1];
    float* out = (float*)d_out;
    unsigned short* cbws = (unsigned short*)d_ws;
    float* cnws = (float*)((char*)d_ws + CB_WS_BYTES);
    float* lossp = (float*)((char*)d_ws + CB_WS_BYTES + 2048);
    unsigned int* donep = (unsigned int*)(lossp + 1);
    hipMemsetAsync(lossp, 0, 8, stream);
    vq_prep<<<2, 256, 0, stream>>>(cb, cbws, cnws);
    vq_main<<<Nz / 128, 256, 0, stream>>>(z, cb, cbws, cnws, out, lossp, donep);
}